// Round 6
// baseline (946.270 us; speedup 1.0000x reference)
//
#include <hip/hip_runtime.h>

#define BB 8
#define NN 4096
#define DD 64
#define SS 1024
#define KK 32
#define R2 0.04f

typedef float f32x2 __attribute__((ext_vector_type(2)));

// One DPP max stage: wv = max(wv, lanes-shifted wv). old = self -> invalid lanes
// contribute identity. row_shr:1,2,4,8 + row_bcast:15,31 -> lane 63 has wave max.
#define DPP_MAXF(wv, CTRL)                                                             \
    {                                                                                  \
        int _o = __builtin_amdgcn_update_dpp(__float_as_int(wv), __float_as_int(wv),   \
                                             CTRL, 0xf, 0xf, false);                   \
        (wv) = fmaxf((wv), __int_as_float(_o));                                        \
    }

// Redundant-FPS design: 256 blocks x 512 thr, one per CU (static LDS 81984 B >
// 160KiB/2 forces 1 block/CU). Block handles batch b = blk>>5 and group chunk
// cs = blk&31: it runs FPS for its batch up to step cs*32+32 (identical,
// deterministic, replicated work), then serves its own 32 groups (ball query +
// output) entirely from its own LDS. NO cross-block synchronization exists.
//
// R6 exchange (informed by R2/R5 measurements): the atomicMax exchange is the
// measured-best (atomics issue PRE-barrier and hide under arrival skew; R5's
// post-barrier butterfly was slower). This round shortens the POST-barrier
// dependent chain instead: the winner lane also writes its candidate's coords
// to a double-buffered per-wave slot pre-barrier; post-barrier each lane issues
// TWO INDEPENDENT LDS reads (red[t] broadcast + wcoord[t&1][lane&7], latencies
// overlap), then 3 readlanes from lane wwin=cand>>9 replace the dependent
// sxyz[far] round-trip entirely. wcoord slots: 8 x 16B covers banks 0..31
// exactly once -> conflict-free. Double-buffering (t&1) is race-free with one
// barrier/step: to overwrite buffer t&1 at step t+2 a wave must pass barrier
// t+1, which requires all waves to have finished their step-t reads.
__global__ __launch_bounds__(512) void fused_kernel(const float* __restrict__ xyz,
                                                    const float* __restrict__ points,
                                                    float* __restrict__ out) {
#pragma clang fp contract(off)
    __shared__ float4 sxyz[NN];                    // 65536 B {x,y,z,pad}
    __shared__ unsigned long long red[SS];         // 8192 B per-step atomic slots
    __shared__ float4 wcoord[2][8];                // 256 B dbuf'd per-wave winner coords
    __shared__ int sfar[SS];                       // 4096 B FPS index history
    __shared__ int bbuf[8][KK];                    // 1024 B per-wave ball lists
    __shared__ unsigned long long lpad[360];       // 2880 B LDS occupancy pad (live)
    // total 65536+8192+256+4096+1024+2880 = 81984 B > 81920 => 1 block/CU guaranteed

    const int tid  = threadIdx.x;
    const int wave = tid >> 6;
    const int lane = tid & 63;
    const int b    = blockIdx.x >> 5;              // batch
    const int cs   = blockIdx.x & 31;              // group chunk within batch
    const float* xb = xyz + (size_t)b * NN * 3;
    const float* pb = points + (size_t)b * NN * DD;

    for (int i = tid; i < SS; i += 512) red[i] = 0ull;      // slots: zero once
    for (int i = tid; i < 360; i += 512) lpad[i] = 0ull;    // touch pad: keep allocated

    // ---- init: 96 contiguous bytes per lane (8 points x 3 floats) via 6x float4 ----
    const float4* xb4 = (const float4*)(xb + tid * 24);
    const float4 q0 = xb4[0], q1 = xb4[1], q2 = xb4[2];
    const float4 q3 = xb4[3], q4 = xb4[4], q5 = xb4[5];

    f32x2 px[4], py[4], pz[4], dist[4];
    px[0] = (f32x2){q0.x, q0.w}; py[0] = (f32x2){q0.y, q1.x}; pz[0] = (f32x2){q0.z, q1.y};
    px[1] = (f32x2){q1.z, q2.y}; py[1] = (f32x2){q1.w, q2.z}; pz[1] = (f32x2){q2.x, q2.w};
    px[2] = (f32x2){q3.x, q3.w}; py[2] = (f32x2){q3.y, q4.x}; pz[2] = (f32x2){q3.z, q4.y};
    px[3] = (f32x2){q4.z, q5.y}; py[3] = (f32x2){q4.w, q5.z}; pz[3] = (f32x2){q5.x, q5.w};
#pragma unroll
    for (int jj = 0; jj < 4; ++jj) {
        const int i0 = tid * 8 + 2 * jj;
        sxyz[i0]     = make_float4(px[jj].x, py[jj].x, pz[jj].x, 0.0f);
        sxyz[i0 + 1] = make_float4(px[jj].y, py[jj].y, pz[jj].y, 0.0f);
        dist[jj] = (f32x2){1e10f, 1e10f};
    }
    __syncthreads();                               // also orders red/lpad init < use

    // ================= FPS (replicated per block; zero global ops) =================
    int far = (int)(unsigned)lpad[0];              // == 0; also keeps lpad live
    const float4 c0 = sxyz[far];                   // one-time centroid-0 coords
    float ccx = c0.x, ccy = c0.y, ccz = c0.z;

    const int tmax = cs * 32 + 32;                 // this block only needs sfar[0..tmax)
    for (int t = 0; t < tmax; ++t) {
        if (tid == 0) sfar[t] = far;               // scan emits pre-update carry
        const f32x2 cx2 = (f32x2){ccx, ccx}, cy2 = (f32x2){ccy, ccy},
                    cz2 = (f32x2){ccz, ccz};

        f32x2 nd[4];
#pragma unroll
        for (int jj = 0; jj < 4; ++jj) {
            // exact ref order: ((dx^2 + dy^2) + dz^2); contract(off) => no FMA
            const f32x2 dx = px[jj] - cx2;
            const f32x2 dy = py[jj] - cy2;
            const f32x2 dz = pz[jj] - cz2;
            const f32x2 d  = (dx * dx + dy * dy) + dz * dz;
            f32x2 m;
            m.x = fminf(dist[jj].x, d.x);          // fmin exact; order-independent
            m.y = fminf(dist[jj].y, d.y);
            dist[jj] = m;
            nd[jj] = m;
        }
        // per-lane max, grouped for v_max3_f32 fusion (4 insts; values non-neg, no NaN)
        const float t0 = fmaxf(fmaxf(nd[0].x, nd[0].y), nd[1].x);   // max3
        const float t1 = fmaxf(fmaxf(nd[1].y, nd[2].x), nd[2].y);   // max3
        const float t2 = fmaxf(nd[3].x, nd[3].y);
        const float bestv = fmaxf(fmaxf(t0, t1), t2);               // max3
        // smallest j achieving it (descending scan => first match wins), carrying the
        // candidate's coords (static indexing only; pre-barrier, off critical path)
        int localj = 0;
        float candx = px[0].x, candy = py[0].x, candz = pz[0].x;
#pragma unroll
        for (int j = 7; j >= 0; --j) {
            const float v = (j & 1) ? nd[j >> 1].y : nd[j >> 1].x;
            if (v == bestv) {
                localj = j;
                candx = (j & 1) ? px[j >> 1].y : px[j >> 1].x;
                candy = (j & 1) ? py[j >> 1].y : py[j >> 1].x;
                candz = (j & 1) ? pz[j >> 1].y : pz[j >> 1].x;
            }
        }

        // wave max via fused DPP f32 max; first matching lane owns the wave's ops
        float wv = bestv;
        DPP_MAXF(wv, 0x111);   // row_shr:1
        DPP_MAXF(wv, 0x112);   // row_shr:2
        DPP_MAXF(wv, 0x114);   // row_shr:4
        DPP_MAXF(wv, 0x118);   // row_shr:8
        DPP_MAXF(wv, 0x142);   // row_bcast:15
        DPP_MAXF(wv, 0x143);   // row_bcast:31
        const float maxw =
            __int_as_float(__builtin_amdgcn_readlane(__float_as_int(wv), 63));

        const unsigned long long hits = __ballot(bestv == maxw);
        const int L = __ffsll(hits) - 1;           // smallest lane == smallest global idx
        if (lane == L) {
            // u64 max == (max val, min index); per-step slot, order-invariant =>
            // identical across replicated blocks. Issued pre-barrier (hidden).
            atomicMax(&red[t],
                      ((unsigned long long)__float_as_uint(bestv) << 32) |
                          (unsigned)~(unsigned)(tid * 8 + localj));
            wcoord[t & 1][wave] = make_float4(candx, candy, candz, 0.0f);
        }
        __syncthreads();                           // the only barrier in the step

        // two INDEPENDENT reads, latencies overlap: winner key (broadcast) and the
        // 8 coord slots (conflict-free). Winner wave = cand>>9 (cand = tid*8+j).
        const unsigned long long kk = red[t];      // ds_read_b64
        const float4 wc = wcoord[t & 1][lane & 7]; // ds_read_b128 (parallel issue)
        far = (int)~(unsigned)kk;                  // next centroid index
        const int wwin = ((unsigned)far) >> 9;     // wave that owns the winner
        ccx = __uint_as_float(__builtin_amdgcn_readlane(__float_as_int(wc.x), wwin));
        ccy = __uint_as_float(__builtin_amdgcn_readlane(__float_as_int(wc.y), wwin));
        ccz = __uint_as_float(__builtin_amdgcn_readlane(__float_as_int(wc.z), wwin));
        // no dependent sxyz[far] read on the critical path
    }
    // sfar[] fully visible: each sfar[t] write precedes that step's barrier.

    // ============ this block's 32 groups: ball query + output, all from LDS ============
#pragma unroll
    for (int i = 0; i < 4; ++i) {
        const int s  = cs * 32 + wave * 4 + i;     // group within batch (s < tmax)
        const int g  = b * SS + s;                 // flat group id
        const int qi = sfar[s];
        const float4 q = sxyz[qi];
        const float qn = __fadd_rn(__fadd_rn(__fmul_rn(q.x, q.x), __fmul_rn(q.y, q.y)),
                                   __fmul_rn(q.z, q.z));

        int total = 0;
        for (int base = 0; base < NN && total < KK; base += 64) {
            const int n = base + lane;
            const float4 p = sxyz[n];              // ds_read_b128; values == global xyz
            const float pn = __fadd_rn(__fadd_rn(__fmul_rn(p.x, p.x), __fmul_rn(p.y, p.y)),
                                       __fmul_rn(p.z, p.z));
            const float dt = __fadd_rn(__fadd_rn(__fmul_rn(q.x, p.x), __fmul_rn(q.y, p.y)),
                                       __fmul_rn(q.z, p.z));
            // exact ref order: d = (-2*dot) + |q|^2 + |p|^2
            const float d = __fadd_rn(__fadd_rn(__fmul_rn(-2.0f, dt), qn), pn);
            const bool hit = !(d > R2);            // include iff d <= r^2
            const unsigned long long mask = __ballot(hit);
            const int before = __popcll(mask & ((1ull << lane) - 1ull));
            const int pos = total + before;
            if (hit && pos < KK) bbuf[wave][pos] = n;
            total += (int)__popcll(mask);
        }
        // pad with first element (wave-synchronous LDS, no barrier needed)
        if (lane < KK) {
            const int v = (lane < total) ? bbuf[wave][lane] : bbuf[wave][0];
            bbuf[wave][lane] = v;
        }

        // new_xyz
        if (lane < 3)
            out[(size_t)g * 3 + lane] = (lane == 0) ? q.x : (lane == 1) ? q.y : q.z;

        // anchor feature columns this lane is responsible for (same for all k)
        const float a1 = (lane >= 3) ? pb[qi * DD + (lane - 3)] : 0.0f;  // cols 67..127
        const float a2 = (lane < 3) ? pb[qi * DD + (61 + lane)] : 0.0f;  // cols 128..130

        float* outp = out + (size_t)BB * SS * 3 + (size_t)g * (KK * 131);
        for (int k = 0; k < KK; ++k) {
            const int idx = bbuf[wave][k];
            const float4 pi = sxyz[idx];
            outp[k * 131 + lane] = pb[idx * DD + lane];                    // cols 0..63
            const float v1 = (lane == 0) ? pi.x
                           : (lane == 1) ? pi.y
                           : (lane == 2) ? pi.z
                                         : a1;                             // cols 64..127
            outp[k * 131 + 64 + lane] = v1;
            if (lane < 3) outp[k * 131 + 128 + lane] = a2;                 // cols 128..130
        }
    }
}

extern "C" void kernel_launch(void* const* d_in, const int* in_sizes, int n_in,
                              void* d_out, int out_size, void* d_ws, size_t ws_size,
                              hipStream_t stream) {
    const float* xyz    = (const float*)d_in[0];   // [B,N,3]
    const float* points = (const float*)d_in[1];   // [B,N,D]
    float* out = (float*)d_out;

    fused_kernel<<<BB * 32, 512, 0, stream>>>(xyz, points, out);
}

// Round 7
// 853.784 us; speedup vs baseline: 1.1083x; 1.1083x over previous
//
#include <hip/hip_runtime.h>

#define BB 8
#define NN 4096
#define DD 64
#define SS 1024
#define KK 32
#define R2 0.04f

typedef float f32x2 __attribute__((ext_vector_type(2)));

// One DPP max stage: wv = max(wv, lanes-shifted wv). old = self -> invalid lanes
// contribute identity. row_shr:1,2,4,8 + row_bcast:15,31 -> lane 63 has wave max.
#define DPP_MAXF(wv, CTRL)                                                             \
    {                                                                                  \
        int _o = __builtin_amdgcn_update_dpp(__float_as_int(wv), __float_as_int(wv),   \
                                             CTRL, 0xf, 0xf, false);                   \
        (wv) = fmaxf((wv), __int_as_float(_o));                                        \
    }

// Redundant-FPS design: 256 blocks x 512 thr, one per CU (static LDS 81984 B >
// 160KiB/2 forces 1 block/CU). Block handles batch b = blk>>5 and chunk cs =
// blk&31: runs FPS for its batch up to step cs*32+32 (identical, deterministic,
// replicated work), then serves its own 32 groups from its own LDS. NO
// cross-block synchronization exists.
//
// R7 (informed by R2/R5/R6 measurements): the B0 exchange (pre-barrier 
// same-address atomicMax; post-barrier red[t] b64 broadcast -> sxyz[far] b128
// broadcast) is the measured-best of four variants — restored EXACTLY.
// This round's single change is WAVE SPECIALIZATION of the FPS loop: waves 0-3
// (one per SIMD) do all compute with 16 points/lane; waves 4-7 execute a
// matched-count barrier-only loop (arrive instantly). This halves the per-SIMD
// issue serialization (the dominant modeled term: two co-resident waves'
// compute serializes between barriers), pays the reduce/scan/chain overhead
// once per SIMD instead of twice, and halves atomic contention (4-way).
// Barrier-count equality: both branches execute exactly tmax __syncthreads().
// Serve phase (all 8 waves) and all numerics are byte-identical to B0.
__global__ __launch_bounds__(512) void fused_kernel(const float* __restrict__ xyz,
                                                    const float* __restrict__ points,
                                                    float* __restrict__ out) {
#pragma clang fp contract(off)
    __shared__ float4 sxyz[NN];                    // 65536 B {x,y,z,pad}
    __shared__ unsigned long long red[SS];         // 8192 B per-step atomic slots
    __shared__ int sfar[SS];                       // 4096 B FPS index history
    __shared__ int bbuf[8][KK];                    // 1024 B per-wave ball lists
    __shared__ unsigned long long lpad[392];       // 3136 B LDS occupancy pad (live)
    // total 65536+8192+4096+1024+3136 = 81984 B > 81920 => 1 block/CU guaranteed

    const int tid  = threadIdx.x;
    const int wave = tid >> 6;
    const int lane = tid & 63;
    const int b    = blockIdx.x >> 5;              // batch
    const int cs   = blockIdx.x & 31;              // group chunk within batch
    const float* xb = xyz + (size_t)b * NN * 3;
    const float* pb = points + (size_t)b * NN * DD;

    for (int i = tid; i < SS; i += 512) red[i] = 0ull;      // slots: zero once
    for (int i = tid; i < 392; i += 512) lpad[i] = 0ull;    // touch pad: keep allocated

    // ---- staging: 96 contiguous bytes per lane (8 points x 3 floats), 6x float4 ----
    {
        const float4* xb4 = (const float4*)(xb + tid * 24);
        const float4 q0 = xb4[0], q1 = xb4[1], q2 = xb4[2];
        const float4 q3 = xb4[3], q4 = xb4[4], q5 = xb4[5];
        float sx[8], sy[8], sz[8];
        sx[0] = q0.x; sy[0] = q0.y; sz[0] = q0.z;
        sx[1] = q0.w; sy[1] = q1.x; sz[1] = q1.y;
        sx[2] = q1.z; sy[2] = q1.w; sz[2] = q2.x;
        sx[3] = q2.y; sy[3] = q2.z; sz[3] = q2.w;
        sx[4] = q3.x; sy[4] = q3.y; sz[4] = q3.z;
        sx[5] = q3.w; sy[5] = q4.x; sz[5] = q4.y;
        sx[6] = q4.z; sy[6] = q4.w; sz[6] = q5.x;
        sx[7] = q5.y; sy[7] = q5.z; sz[7] = q5.w;
#pragma unroll
        for (int j = 0; j < 8; ++j)
            sxyz[tid * 8 + j] = make_float4(sx[j], sy[j], sz[j], 0.0f);
    }
    __syncthreads();                               // staging + red/lpad init visible

    const int tmax = cs * 32 + 32;                 // this block only needs sfar[0..tmax)

    // ================= FPS (replicated per block; zero global ops) =================
    if (tid < 256) {
        // ---- compute waves 0-3 (one per SIMD): 16 points per lane, from LDS ----
        f32x2 px[8], py[8], pz[8], dist[8];
#pragma unroll
        for (int jj = 0; jj < 8; ++jj) {
            const float4 p0 = sxyz[tid * 16 + 2 * jj];
            const float4 p1 = sxyz[tid * 16 + 2 * jj + 1];
            px[jj] = (f32x2){p0.x, p1.x};
            py[jj] = (f32x2){p0.y, p1.y};
            pz[jj] = (f32x2){p0.z, p1.z};
            dist[jj] = (f32x2){1e10f, 1e10f};
        }
        int far = (int)(unsigned)lpad[0];          // == 0; also keeps lpad live

        for (int t = 0; t < tmax; ++t) {
            if (tid == 0) sfar[t] = far;           // scan emits pre-update carry
            const float4 c = sxyz[far];            // one ds_read_b128 (broadcast)
            const f32x2 cx2 = (f32x2){c.x, c.x}, cy2 = (f32x2){c.y, c.y},
                        cz2 = (f32x2){c.z, c.z};

            f32x2 nd[8];
#pragma unroll
            for (int jj = 0; jj < 8; ++jj) {
                // exact ref order: ((dx^2 + dy^2) + dz^2); contract(off) => no FMA
                const f32x2 dx = px[jj] - cx2;
                const f32x2 dy = py[jj] - cy2;
                const f32x2 dz = pz[jj] - cz2;
                const f32x2 d  = (dx * dx + dy * dy) + dz * dz;
                f32x2 m;
                m.x = fminf(dist[jj].x, d.x);      // fmin exact; order-independent
                m.y = fminf(dist[jj].y, d.y);
                dist[jj] = m;
                nd[jj] = m;
            }
            // per-lane max over 16, grouped for v_max3_f32 fusion (values >=0, no NaN)
            const float m0 = fmaxf(fmaxf(nd[0].x, nd[0].y), nd[1].x);
            const float m1 = fmaxf(fmaxf(nd[1].y, nd[2].x), nd[2].y);
            const float m2 = fmaxf(fmaxf(nd[3].x, nd[3].y), nd[4].x);
            const float m3 = fmaxf(fmaxf(nd[4].y, nd[5].x), nd[5].y);
            const float m4 = fmaxf(fmaxf(nd[6].x, nd[6].y), nd[7].x);
            const float A  = fmaxf(fmaxf(m0, m1), m2);
            const float B  = fmaxf(fmaxf(m3, m4), nd[7].y);
            const float bestv = fmaxf(A, B);
            // smallest j achieving it (descending scan => first match wins)
            int localj = 0;
#pragma unroll
            for (int j = 15; j >= 0; --j) {
                const float v = (j & 1) ? nd[j >> 1].y : nd[j >> 1].x;
                if (v == bestv) localj = j;
            }

            // wave max via fused DPP f32 max; first matching lane owns the atomic
            float wv = bestv;
            DPP_MAXF(wv, 0x111);   // row_shr:1
            DPP_MAXF(wv, 0x112);   // row_shr:2
            DPP_MAXF(wv, 0x114);   // row_shr:4
            DPP_MAXF(wv, 0x118);   // row_shr:8
            DPP_MAXF(wv, 0x142);   // row_bcast:15
            DPP_MAXF(wv, 0x143);   // row_bcast:31
            const float maxw =
                __int_as_float(__builtin_amdgcn_readlane(__float_as_int(wv), 63));

            const unsigned long long hits = __ballot(bestv == maxw);
            const int L = __ffsll(hits) - 1;       // smallest lane == smallest global idx
            if (lane == L) {
                // u64 max == (max val, min index); order-invariant => identical
                // across replicated blocks. Issued pre-barrier (hidden).
                atomicMax(&red[t],
                          ((unsigned long long)__float_as_uint(bestv) << 32) |
                              (unsigned)~(unsigned)(tid * 16 + localj));
            }
            __syncthreads();                       // the only barrier in the step
            far = (int)~(unsigned)red[t];          // broadcast ds_read_b64
        }
    } else {
        // ---- spectator waves 4-7: matched-count barrier loop, instant arrival ----
        for (int t = 0; t < tmax; ++t) __syncthreads();
    }
    // sfar[] fully visible: each sfar[t] write precedes that step's barrier.

    // ============ this block's 32 groups: ball query + output, all from LDS ============
#pragma unroll
    for (int i = 0; i < 4; ++i) {
        const int s  = cs * 32 + wave * 4 + i;     // group within batch (s < tmax)
        const int g  = b * SS + s;                 // flat group id
        const int qi = sfar[s];
        const float4 q = sxyz[qi];
        const float qn = __fadd_rn(__fadd_rn(__fmul_rn(q.x, q.x), __fmul_rn(q.y, q.y)),
                                   __fmul_rn(q.z, q.z));

        int total = 0;
        for (int base = 0; base < NN && total < KK; base += 64) {
            const int n = base + lane;
            const float4 p = sxyz[n];              // ds_read_b128; values == global xyz
            const float pn = __fadd_rn(__fadd_rn(__fmul_rn(p.x, p.x), __fmul_rn(p.y, p.y)),
                                       __fmul_rn(p.z, p.z));
            const float dt = __fadd_rn(__fadd_rn(__fmul_rn(q.x, p.x), __fmul_rn(q.y, p.y)),
                                       __fmul_rn(q.z, p.z));
            // exact ref order: d = (-2*dot) + |q|^2 + |p|^2
            const float d = __fadd_rn(__fadd_rn(__fmul_rn(-2.0f, dt), qn), pn);
            const bool hit = !(d > R2);            // include iff d <= r^2
            const unsigned long long mask = __ballot(hit);
            const int before = __popcll(mask & ((1ull << lane) - 1ull));
            const int pos = total + before;
            if (hit && pos < KK) bbuf[wave][pos] = n;
            total += (int)__popcll(mask);
        }
        // pad with first element (wave-synchronous LDS, no barrier needed)
        if (lane < KK) {
            const int v = (lane < total) ? bbuf[wave][lane] : bbuf[wave][0];
            bbuf[wave][lane] = v;
        }

        // new_xyz
        if (lane < 3)
            out[(size_t)g * 3 + lane] = (lane == 0) ? q.x : (lane == 1) ? q.y : q.z;

        // anchor feature columns this lane is responsible for (same for all k)
        const float a1 = (lane >= 3) ? pb[qi * DD + (lane - 3)] : 0.0f;  // cols 67..127
        const float a2 = (lane < 3) ? pb[qi * DD + (61 + lane)] : 0.0f;  // cols 128..130

        float* outp = out + (size_t)BB * SS * 3 + (size_t)g * (KK * 131);
        for (int k = 0; k < KK; ++k) {
            const int idx = bbuf[wave][k];
            const float4 pi = sxyz[idx];
            outp[k * 131 + lane] = pb[idx * DD + lane];                    // cols 0..63
            const float v1 = (lane == 0) ? pi.x
                           : (lane == 1) ? pi.y
                           : (lane == 2) ? pi.z
                                         : a1;                             // cols 64..127
            outp[k * 131 + 64 + lane] = v1;
            if (lane < 3) outp[k * 131 + 128 + lane] = a2;                 // cols 128..130
        }
    }
}

extern "C" void kernel_launch(void* const* d_in, const int* in_sizes, int n_in,
                              void* d_out, int out_size, void* d_ws, size_t ws_size,
                              hipStream_t stream) {
    const float* xyz    = (const float*)d_in[0];   // [B,N,3]
    const float* points = (const float*)d_in[1];   // [B,N,D]
    float* out = (float*)d_out;

    fused_kernel<<<BB * 32, 512, 0, stream>>>(xyz, points, out);
}

// Round 8
// 776.050 us; speedup vs baseline: 1.2193x; 1.1002x over previous
//
#include <hip/hip_runtime.h>

#define BB 8
#define NN 4096
#define DD 64
#define SS 1024
#define KK 32
#define R2 0.04f

typedef float f32x2 __attribute__((ext_vector_type(2)));

// One DPP max stage: wv = max(wv, lanes-shifted wv). old = self -> invalid lanes
// contribute identity. row_shr:1,2,4,8 + row_bcast:15,31 -> lane 63 has wave max.
#define DPP_MAXF(wv, CTRL)                                                             \
    {                                                                                  \
        int _o = __builtin_amdgcn_update_dpp(__float_as_int(wv), __float_as_int(wv),   \
                                             CTRL, 0xf, 0xf, false);                   \
        (wv) = fmaxf((wv), __int_as_float(_o));                                        \
    }

// Packed f32 helpers (guaranteed VOP3P; per-component semantics are the IEEE
// scalar ops, so results are bit-identical to the scalar formulation).
static __device__ __forceinline__ f32x2 pk_add(f32x2 a, f32x2 b) {
    f32x2 d;
    asm("v_pk_add_f32 %0, %1, %2" : "=v"(d) : "v"(a), "v"(b));
    return d;
}
static __device__ __forceinline__ f32x2 pk_sq(f32x2 a) {
    f32x2 d;
    asm("v_pk_mul_f32 %0, %1, %1" : "=v"(d) : "v"(a));
    return d;
}

// Redundant-FPS design: 256 blocks x 512 thr, one per CU (static LDS 82176 B >
// 160KiB/2 forces 1 block/CU). Block handles batch b = blk>>5 and chunk cs =
// blk&31: runs FPS for its batch up to step cs*32+32 (identical, deterministic,
// replicated work — fminf and u64-atomicMax are order-invariant), then serves
// its own 32 groups (ball query + output) entirely from its own LDS. NO
// cross-block synchronization exists; the FPS loop has zero global-memory ops.
//
// R8 (informed by R2/R5/R6/R7 measurements): four exchange/specialization
// variants all LOST to the B0 exchange (pre-barrier same-address atomicMax;
// post-barrier red[t] b64 broadcast -> sxyz[far] b128 broadcast). Measured
// lesson: step time = SUM of all serial segments (waves are barrier-locked to
// the same phase; nothing hides), so only op REMOVALS win. This round restores
// B0 exactly and removes ~40 scalar VALU insts/wave/step by forcing the
// distance update through v_pk_add/mul_f32 (subtract = add of the per-step
// negated centroid; bit-exact). Plus the inert early-exit tmax.
__global__ __launch_bounds__(512) void fused_kernel(const float* __restrict__ xyz,
                                                    const float* __restrict__ points,
                                                    float* __restrict__ out) {
#pragma clang fp contract(off)
    __shared__ float4 sxyz[NN];                    // 64 KB {x,y,z,pad}
    __shared__ unsigned long long red[SS + 416];   // 11.25 KB (416 = LDS occupancy pad)
    __shared__ int sfar[SS];                       // 4 KB
    __shared__ int bbuf[8][KK];                    // 1 KB per-wave ball lists
    // total 82176 B (same as the verified 739us baseline) => 1 block/CU

    const int tid  = threadIdx.x;
    const int wave = tid >> 6;
    const int lane = tid & 63;
    const int b    = blockIdx.x >> 5;              // batch
    const int cs   = blockIdx.x & 31;              // group chunk within batch
    const float* xb = xyz + (size_t)b * NN * 3;
    const float* pb = points + (size_t)b * NN * DD;

    for (int i = tid; i < SS; i += 512) red[i] = 0ull;   // slots: zero once

    // ---- init: 96 contiguous bytes per lane (8 points x 3 floats) via 6x float4 ----
    const float4* xb4 = (const float4*)(xb + tid * 24);
    const float4 q0 = xb4[0], q1 = xb4[1], q2 = xb4[2];
    const float4 q3 = xb4[3], q4 = xb4[4], q5 = xb4[5];

    f32x2 px[4], py[4], pz[4], dist[4];
    px[0] = (f32x2){q0.x, q0.w}; py[0] = (f32x2){q0.y, q1.x}; pz[0] = (f32x2){q0.z, q1.y};
    px[1] = (f32x2){q1.z, q2.y}; py[1] = (f32x2){q1.w, q2.z}; pz[1] = (f32x2){q2.x, q2.w};
    px[2] = (f32x2){q3.x, q3.w}; py[2] = (f32x2){q3.y, q4.x}; pz[2] = (f32x2){q3.z, q4.y};
    px[3] = (f32x2){q4.z, q5.y}; py[3] = (f32x2){q4.w, q5.z}; pz[3] = (f32x2){q5.x, q5.w};
#pragma unroll
    for (int jj = 0; jj < 4; ++jj) {
        const int i0 = tid * 8 + 2 * jj;
        sxyz[i0]     = make_float4(px[jj].x, py[jj].x, pz[jj].x, 0.0f);
        sxyz[i0 + 1] = make_float4(px[jj].y, py[jj].y, pz[jj].y, 0.0f);
        dist[jj] = (f32x2){1e10f, 1e10f};
    }
    __syncthreads();

    // ================= FPS (replicated per block; zero global ops) =================
    int far = 0;
    const int tmax = cs * 32 + 32;                 // this block only needs sfar[0..tmax)
    for (int t = 0; t < tmax; ++t) {
        if (tid == 0) sfar[t] = far;               // scan emits pre-update carry
        const float4 c = sxyz[far];                // one ds_read_b128 (broadcast)
        // negated centroid, once per step: p - c == p + (-c) exactly (IEEE)
        const f32x2 ncx2 = (f32x2){-c.x, -c.x}, ncy2 = (f32x2){-c.y, -c.y},
                    ncz2 = (f32x2){-c.z, -c.z};

        f32x2 nd[4];
#pragma unroll
        for (int jj = 0; jj < 4; ++jj) {
            // exact ref order: ((dx^2 + dy^2) + dz^2); pk ops, no FMA, no contract
            const f32x2 dx = pk_add(px[jj], ncx2);
            const f32x2 dy = pk_add(py[jj], ncy2);
            const f32x2 dz = pk_add(pz[jj], ncz2);
            const f32x2 d  = pk_add(pk_add(pk_sq(dx), pk_sq(dy)), pk_sq(dz));
            f32x2 m;
            m.x = fminf(dist[jj].x, d.x);          // fmin exact; order-independent
            m.y = fminf(dist[jj].y, d.y);
            dist[jj] = m;
            nd[jj] = m;
        }
        // per-lane max (tree; values non-negative, no NaN) — B0's exact shape
        const float bestv =
            fmaxf(fmaxf(fmaxf(nd[0].x, nd[0].y), fmaxf(nd[1].x, nd[1].y)),
                  fmaxf(fmaxf(nd[2].x, nd[2].y), fmaxf(nd[3].x, nd[3].y)));
        // smallest j achieving it (descending scan => first match wins)
        int localj = 0;
#pragma unroll
        for (int j = 7; j >= 0; --j) {
            const float v = (j & 1) ? nd[j >> 1].y : nd[j >> 1].x;
            if (v == bestv) localj = j;
        }

        // wave max via fused DPP f32 max; recover first-lane index via ballot+ffs
        float wv = bestv;
        DPP_MAXF(wv, 0x111);   // row_shr:1
        DPP_MAXF(wv, 0x112);   // row_shr:2
        DPP_MAXF(wv, 0x114);   // row_shr:4
        DPP_MAXF(wv, 0x118);   // row_shr:8
        DPP_MAXF(wv, 0x142);   // row_bcast:15
        DPP_MAXF(wv, 0x143);   // row_bcast:31
        const float maxw =
            __int_as_float(__builtin_amdgcn_readlane(__float_as_int(wv), 63));

        const unsigned long long hits = __ballot(bestv == maxw);
        const int L = __ffsll(hits) - 1;         // smallest lane == smallest global idx
        const int candv = tid * 8 + localj;      // global point index
        const int cand  = __builtin_amdgcn_readlane(candv, L);

        // leaders race into the per-step slot; u64 max == (max val, min index);
        // final value is order-invariant => identical across replicated blocks
        if (lane == 0) {
            const unsigned long long p =
                ((unsigned long long)__float_as_uint(maxw) << 32) | (unsigned)(~cand);
            atomicMax(&red[t], p);
        }
        __syncthreads();                         // the only barrier in the step
        far = (int)(~(unsigned)red[t]);          // broadcast ds_read_b64
    }
    // sfar[] fully visible: each sfar[t] write precedes that step's barrier.

    // ============ this block's 32 groups: ball query + output, all from LDS ============
#pragma unroll
    for (int i = 0; i < 4; ++i) {
        const int s  = cs * 32 + wave * 4 + i;   // group within batch (s < tmax)
        const int g  = b * SS + s;               // flat group id
        const int qi = sfar[s];
        const float4 q = sxyz[qi];
        const float qn = __fadd_rn(__fadd_rn(__fmul_rn(q.x, q.x), __fmul_rn(q.y, q.y)),
                                   __fmul_rn(q.z, q.z));

        int total = 0;
        for (int base = 0; base < NN && total < KK; base += 64) {
            const int n = base + lane;
            const float4 p = sxyz[n];            // ds_read_b128; values == global xyz
            const float pn = __fadd_rn(__fadd_rn(__fmul_rn(p.x, p.x), __fmul_rn(p.y, p.y)),
                                       __fmul_rn(p.z, p.z));
            const float dt = __fadd_rn(__fadd_rn(__fmul_rn(q.x, p.x), __fmul_rn(q.y, p.y)),
                                       __fmul_rn(q.z, p.z));
            // exact ref order: d = (-2*dot) + |q|^2 + |p|^2
            const float d = __fadd_rn(__fadd_rn(__fmul_rn(-2.0f, dt), qn), pn);
            const bool hit = !(d > R2);          // include iff d <= r^2
            const unsigned long long mask = __ballot(hit);
            const int before = __popcll(mask & ((1ull << lane) - 1ull));
            const int pos = total + before;
            if (hit && pos < KK) bbuf[wave][pos] = n;
            total += (int)__popcll(mask);
        }
        // pad with first element (wave-synchronous LDS, no barrier needed)
        if (lane < KK) {
            const int v = (lane < total) ? bbuf[wave][lane] : bbuf[wave][0];
            bbuf[wave][lane] = v;
        }

        // new_xyz
        if (lane < 3)
            out[(size_t)g * 3 + lane] = (lane == 0) ? q.x : (lane == 1) ? q.y : q.z;

        // anchor feature columns this lane is responsible for (same for all k)
        const float a1 = (lane >= 3) ? pb[qi * DD + (lane - 3)] : 0.0f;  // cols 67..127
        const float a2 = (lane < 3) ? pb[qi * DD + (61 + lane)] : 0.0f;  // cols 128..130

        float* outp = out + (size_t)BB * SS * 3 + (size_t)g * (KK * 131);
        for (int k = 0; k < KK; ++k) {
            const int idx = bbuf[wave][k];
            const float4 pi = sxyz[idx];
            outp[k * 131 + lane] = pb[idx * DD + lane];                    // cols 0..63
            const float v1 = (lane == 0) ? pi.x
                           : (lane == 1) ? pi.y
                           : (lane == 2) ? pi.z
                                         : a1;                             // cols 64..127
            outp[k * 131 + 64 + lane] = v1;
            if (lane < 3) outp[k * 131 + 128 + lane] = a2;                 // cols 128..130
        }
    }
}

extern "C" void kernel_launch(void* const* d_in, const int* in_sizes, int n_in,
                              void* d_out, int out_size, void* d_ws, size_t ws_size,
                              hipStream_t stream) {
    const float* xyz    = (const float*)d_in[0];   // [B,N,3]
    const float* points = (const float*)d_in[1];   // [B,N,D]
    float* out = (float*)d_out;

    fused_kernel<<<BB * 32, 512, 0, stream>>>(xyz, points, out);
}